// Round 2
// baseline (2660.380 us; speedup 1.0000x reference)
//
#include <hip/hip_runtime.h>
#include <math.h>

#define BATCH 8
#define NN 128          // nodes
#define FS 128
#define FV 64
#define NB 8
#define HID 64
#define ROUT 320

// ---- workspace layout (float offsets) ----
#define SZ_S   (BATCH*FS*NN)        // 131072
#define SZ_V   (BATCH*FV*3*NN)      // 196608
#define SZ_T   (BATCH*FV*NN)        // 65536
#define SZ_W2T (2*ROUT*HID)         // 40960
#define OFF_SA 0
#define OFF_SB (OFF_SA+SZ_S)
#define OFF_VA (OFF_SB+SZ_S)
#define OFF_VB (OFF_VA+SZ_V)
#define OFF_T0 (OFF_VB+SZ_V)
#define OFF_T1 (OFF_T0+SZ_T)
#define OFF_W2T (OFF_T1+SZ_T)
#define OFF_COM (OFF_W2T+SZ_W2T)    // 24 floats

__device__ __forceinline__ float silu_f(float x){ return x * (1.0f/(1.0f + __expf(-x))); }

__device__ __forceinline__ float waveRed(float v){
  v += __shfl_xor(v, 32, 64);
  v += __shfl_xor(v, 16, 64);
  v += __shfl_xor(v,  8, 64);
  v += __shfl_xor(v,  4, 64);
  v += __shfl_xor(v,  2, 64);
  v += __shfl_xor(v,  1, 64);
  return v;
}

__device__ __forceinline__ float dot64(const float* hid, const float* __restrict__ w){
  float a0=0.f,a1=0.f,a2=0.f,a3=0.f;
  #pragma unroll
  for(int j=0;j<64;j+=4){
    a0 = fmaf(hid[j+0], w[j+0], a0);
    a1 = fmaf(hid[j+1], w[j+1], a1);
    a2 = fmaf(hid[j+2], w[j+2], a2);
    a3 = fmaf(hid[j+3], w[j+3], a3);
  }
  return (a0+a1)+(a2+a3);
}

// init: sA = species broadcast (transposed [b][f][n]); VA = 0; t0 = species@Wsv0
// broadcast ([b][g][n]); Wr2 transposed to [l][c][j]; com[b][3] = mean(pos)
__global__ void init_kernel(const float* __restrict__ x, const float* __restrict__ species,
                            const float* __restrict__ Wr2, const float* __restrict__ Wsv0,
                            float* __restrict__ ws)
{
  int idx = blockIdx.x*blockDim.x + threadIdx.x;
  const int total = SZ_S + SZ_V + SZ_T + SZ_W2T + 24;
  for (; idx < total; idx += gridDim.x*blockDim.x) {
    int t = idx;
    if (t < SZ_S) { int f = (t>>7)&127; ws[OFF_SA+t] = species[f]; continue; }
    t -= SZ_S;
    if (t < SZ_V) { ws[OFF_VA+t] = 0.f; continue; }
    t -= SZ_V;
    if (t < SZ_T) {
      int g = (t>>7)&63;
      float a = 0.f;
      for (int f=0; f<FS; f++) a = fmaf(species[f], Wsv0[f*FV+g], a);
      ws[OFF_T0+t] = a; continue;
    }
    t -= SZ_T;
    if (t < SZ_W2T) {
      int j = t&63; int c = (t>>6)%ROUT; int l = t/(ROUT*HID);
      ws[OFF_W2T+t] = Wr2[l*HID*ROUT + j*ROUT + c]; continue;
    }
    t -= SZ_W2T;
    { int bb=t/3, c3=t-bb*3;
      float a=0.f;
      for(int n=0;n<NN;n++) a += x[(bb*NN+n)*3+c3];
      ws[OFF_COM+t] = a*(1.0f/128.0f); }
  }
}

// one block per (batch, receiver k); 256 threads = 4 waves.
// wave w: sender-half sh=w&1 (senders sh*64+lane), channel-half ch=w>>1.
__global__ __launch_bounds__(256, 4) void layer_kernel(
    const float* __restrict__ pos,
    const float* __restrict__ sInT,   // [b][f][n]
    const float* __restrict__ vInT,   // [b][f][c3][n]
    const float* __restrict__ tInT,   // [b][g][n]
    float* __restrict__ sOutT,
    float* __restrict__ vOutT,
    float* __restrict__ tOutT,        // may be null
    const float* __restrict__ Wr1l,   // (8,64)
    const float* __restrict__ W2Tl,   // (320,64) transposed
    const float* __restrict__ WmixSl, // (192,128)
    const float* __restrict__ WmixVl, // (128,64)
    const float* __restrict__ WsvNext)// (128,64) or null
{
  const int tid  = threadIdx.x;
  const int b    = blockIdx.x >> 7;
  const int k    = blockIdx.x & 127;
  const int w    = tid >> 6;
  const int lane = tid & 63;
  const int sh   = w & 1;       // sender half
  const int ch   = w >> 1;      // channel half
  const int i    = sh*64 + lane;

  __shared__ float aggP[2][576];
  __shared__ float aggC[576];
  __shared__ float sNew[FS];

  // ---- edge geometry (v = pos[k] - pos[i]) ----
  const float* pb = pos + b*NN*3;
  float pkx=pb[k*3+0], pky=pb[k*3+1], pkz=pb[k*3+2];
  float pix=pb[i*3+0], piy=pb[i*3+1], piz=pb[i*3+2];
  float vx=pkx-pix, vy=pky-piy, vz=pkz-piz;
  float r = sqrtf(vx*vx+vy*vy+vz*vz) + 1e-8f;
  float inv = 1.0f/r;
  float hxv=vx*inv, hyv=vy*inv, hzv=vz*inv;
  float u = r*0.2f;
  float env = 0.0f;
  if (u < 1.0f && i != k){
    float u2=u*u, u6=u2*u2*u2;
    env = 1.0f - 28.0f*u6 + 48.0f*u6*u - 21.0f*u6*u2;
  }
  float coef = 0.6324555320336759f * inv * env;   // sqrt(2/5)/r * env  (0 for self/out-of-range)
  float arg  = r * 0.6283185307179586f;           // pi*r/5

  // ---- hidden = silu(rb @ Wr1) : per-lane registers ----
  float hid[HID];
  {
    float rb[NB];
    #pragma unroll
    for(int n=0;n<NB;n++) rb[n] = coef * __sinf(arg*(float)(n+1));
    #pragma unroll
    for(int j=0;j<HID;j++) hid[j]=0.f;
    #pragma unroll
    for(int n=0;n<NB;n++){
      const float* wr = Wr1l + n*HID;
      float rn = rb[n];
      #pragma unroll
      for(int j=0;j<HID;j++) hid[j] = fmaf(rn, wr[j], hid[j]);
    }
    #pragma unroll
    for(int j=0;j<HID;j++) hid[j] = silu_f(hid[j]);
  }

  const float* sIb = sInT + b*FS*NN;
  const float* vIb = vInT + b*FV*3*NN;
  const float* tIb = tInT + b*FV*NN;

  // ---- Loop A: c in [ch*64, ch*64+64)  m0a = h * s[i,c] ----
  for (int c=ch*64; c<ch*64+64; c+=4){
    float h0 = dot64(hid, W2Tl + (c+0)*HID);
    float h1 = dot64(hid, W2Tl + (c+1)*HID);
    float h2 = dot64(hid, W2Tl + (c+2)*HID);
    float h3 = dot64(hid, W2Tl + (c+3)*HID);
    float g0 = waveRed(h0 * sIb[(c+0)*NN+i]);
    float g1 = waveRed(h1 * sIb[(c+1)*NN+i]);
    float g2 = waveRed(h2 * sIb[(c+2)*NN+i]);
    float g3 = waveRed(h3 * sIb[(c+3)*NN+i]);
    if (lane==0){ aggP[sh][c]=g0; aggP[sh][c+1]=g1; aggP[sh][c+2]=g2; aggP[sh][c+3]=g3; }
  }
  // ---- Loop B: f in [ch*32, ch*32+32)  m0b = h * (V[i,f,:]·vhat) ----
  for (int f=ch*32; f<ch*32+32; f+=2){
    int c = FS + f;
    float h0 = dot64(hid, W2Tl + (c+0)*HID);
    float h1 = dot64(hid, W2Tl + (c+1)*HID);
    const float* vf0 = vIb + (f+0)*3*NN;
    const float* vf1 = vIb + (f+1)*3*NN;
    float dv0 = vf0[i]*hxv + vf0[NN+i]*hyv + vf0[2*NN+i]*hzv;
    float dv1 = vf1[i]*hxv + vf1[NN+i]*hyv + vf1[2*NN+i]*hzv;
    float g0 = waveRed(h0*dv0);
    float g1 = waveRed(h1*dv1);
    if (lane==0){ aggP[sh][c]=g0; aggP[sh][c+1]=g1; }
  }
  // ---- Loop C1: f in [ch*32, ch*32+32)  m1a = h * t[i,f] * vhat ----
  for (int f=ch*32; f<ch*32+32; f++){
    int c = FS+FV+f;
    float h = dot64(hid, W2Tl + c*HID);
    float tb = h * tIb[f*NN+i];
    float g0 = waveRed(tb*hxv);
    float g1 = waveRed(tb*hyv);
    float g2 = waveRed(tb*hzv);
    if (lane==0){ int s0=192+f*3; aggP[sh][s0]=g0; aggP[sh][s0+1]=g1; aggP[sh][s0+2]=g2; }
  }
  // ---- Loop C2: f in [ch*32, ch*32+32)  m1b = h * V[i,f,:] ----
  for (int f=ch*32; f<ch*32+32; f++){
    int c = FS+2*FV+f;
    float h = dot64(hid, W2Tl + c*HID);
    const float* vf = vIb + f*3*NN;
    float g0 = waveRed(h*vf[i]);
    float g1 = waveRed(h*vf[NN+i]);
    float g2 = waveRed(h*vf[2*NN+i]);
    if (lane==0){ int s0=384+f*3; aggP[sh][s0]=g0; aggP[sh][s0+1]=g1; aggP[sh][s0+2]=g2; }
  }

  __syncthreads();
  for (int c=tid; c<576; c+=256) aggC[c] = (aggP[0][c]+aggP[1][c]) * (1.0f/128.0f);
  __syncthreads();

  // ---- epilogue: s update (threads 0..127, feature = tid) ----
  if (tid < FS){
    float sk_in = sIb[tid*NN + k];
    float a0=0.f, a1=0.f;
    #pragma unroll 4
    for(int c=0;c<192;c+=2){
      a0 = fmaf(aggC[c],   WmixSl[c*FS+tid],     a0);
      a1 = fmaf(aggC[c+1], WmixSl[(c+1)*FS+tid], a1);
    }
    float sn = sk_in + silu_f(a0+a1);
    sNew[tid] = sn;
    sOutT[(b*FS+tid)*NN + k] = sn;
  }
  // ---- epilogue: V update (threads 0..191, idx = g*3+c3) ----
  if (tid < 192){
    int g = tid/3, c3 = tid-g*3;
    float a0=0.f, a1=0.f;
    #pragma unroll 4
    for(int f=0; f<128; f+=2){
      a0 = fmaf(aggC[192+f*3+c3],     WmixVl[f*FV+g],     a0);
      a1 = fmaf(aggC[192+(f+1)*3+c3], WmixVl[(f+1)*FV+g], a1);
    }
    float vin = vIb[tid*NN + k];
    vOutT[(b*FV*3 + tid)*NN + k] = vin + (a0+a1);
  }
  __syncthreads();
  // ---- epilogue: t for next layer (from updated s) ----
  if (tOutT != nullptr && tid < FV){
    float a0=0.f, a1=0.f;
    #pragma unroll 4
    for(int f=0;f<FS;f+=2){
      a0 = fmaf(sNew[f],   WsvNext[f*FV+tid],     a0);
      a1 = fmaf(sNew[f+1], WsvNext[(f+1)*FV+tid], a1);
    }
    tOutT[(b*FV+tid)*NN + k] = a0+a1;
  }
}

__global__ __launch_bounds__(128, 2) void out_kernel(
    const float* __restrict__ sT,
    const float* __restrict__ vT,
    const float* __restrict__ WoutS,
    const float* __restrict__ WoutV,
    const float* __restrict__ comv,
    float* __restrict__ out)
{
  const int tid = threadIdx.x;
  const int b = blockIdx.x >> 7;
  const int k = blockIdx.x & 127;
  __shared__ float sL[FS];
  __shared__ float vL[FV*3];
  sL[tid] = sT[(b*FS+tid)*NN + k];
  for (int idx=tid; idx<192; idx+=128) vL[idx] = vT[(b*FV*3+idx)*NN + k];
  __syncthreads();
  {
    float a0=0.f, a1=0.f;
    #pragma unroll 4
    for(int f=0;f<FS;f+=2){
      a0 = fmaf(sL[f],   WoutS[f*FS+tid],     a0);
      a1 = fmaf(sL[f+1], WoutS[(f+1)*FS+tid], a1);
    }
    out[BATCH*NN*FV*3 + (b*NN+k)*FS + tid] = a0+a1;
  }
  for (int idx=tid; idx<192; idx+=128){
    int g = idx/3, c3 = idx-g*3;
    float a = comv[b*3+c3];
    #pragma unroll 4
    for(int f=0;f<FV;f++) a = fmaf(vL[f*3+c3], WoutV[f*FV+g], a);
    out[(b*NN+k)*FV*3 + idx] = a;
  }
}

extern "C" void kernel_launch(void* const* d_in, const int* in_sizes, int n_in,
                              void* d_out, int out_size, void* d_ws, size_t ws_size,
                              hipStream_t stream)
{
  const float* x       = (const float*)d_in[0];
  const float* species = (const float*)d_in[1];
  const float* Wr1     = (const float*)d_in[2];
  const float* Wr2     = (const float*)d_in[3];
  const float* Wsv     = (const float*)d_in[4];
  const float* WmixS   = (const float*)d_in[5];
  const float* WmixV   = (const float*)d_in[6];
  const float* WoutS   = (const float*)d_in[7];
  const float* WoutV   = (const float*)d_in[8];
  float* ws  = (float*)d_ws;
  float* out = (float*)d_out;

  float* sA  = ws + OFF_SA;
  float* sB  = ws + OFF_SB;
  float* vA  = ws + OFF_VA;
  float* vB  = ws + OFF_VB;
  float* t0  = ws + OFF_T0;
  float* t1  = ws + OFF_T1;
  float* w2t = ws + OFF_W2T;
  float* com = ws + OFF_COM;

  const int initTotal = SZ_S + SZ_V + SZ_T + SZ_W2T + 24;
  init_kernel<<<(initTotal+255)/256, 256, 0, stream>>>(x, species, Wr2, Wsv, ws);

  // layer 0: reads sA/vA/t0, writes sB/vB and t1 (t for layer 1 from updated s)
  layer_kernel<<<BATCH*NN, 256, 0, stream>>>(x, sA, vA, t0, sB, vB, t1,
      Wr1,        w2t,          WmixS,           WmixV,          Wsv + FS*FV);
  // layer 1: reads sB/vB/t1, writes sA/vA
  layer_kernel<<<BATCH*NN, 256, 0, stream>>>(x, sB, vB, t1, sA, vA, nullptr,
      Wr1 + NB*HID, w2t + ROUT*HID, WmixS + 192*FS, WmixV + 128*FV, nullptr);

  out_kernel<<<BATCH*NN, 128, 0, stream>>>(sA, vA, WoutS, WoutV, com, out);
}

// Round 3
// 669.159 us; speedup vs baseline: 3.9757x; 3.9757x over previous
//
#include <hip/hip_runtime.h>
#include <math.h>

#define BATCH 8
#define NN 128          // nodes
#define FS 128
#define FV 64
#define NB 8
#define HID 64
#define ROUT 320
#define HSTR 68         // hid LDS row stride in floats (pad 64->68 kills write conflicts)

// ---- workspace layout (float offsets); s:[b][n][f], V:[b][n][f*3+c3], t:[b][n][g] ----
#define SZ_S   (BATCH*NN*FS)
#define SZ_V   (BATCH*NN*FV*3)
#define SZ_T   (BATCH*NN*FV)
#define SZ_W2T (2*ROUT*HID)
#define OFF_SA 0
#define OFF_SB (OFF_SA+SZ_S)
#define OFF_VA (OFF_SB+SZ_S)
#define OFF_VB (OFF_VA+SZ_V)
#define OFF_T0 (OFF_VB+SZ_V)
#define OFF_T1 (OFF_T0+SZ_T)
#define OFF_W2T (OFF_T1+SZ_T)
#define OFF_COM (OFF_W2T+SZ_W2T)    // 24 floats

__device__ __forceinline__ float silu_f(float x){ return x * (1.0f/(1.0f + __expf(-x))); }

__global__ void init_kernel(const float* __restrict__ x, const float* __restrict__ species,
                            const float* __restrict__ Wr2, const float* __restrict__ Wsv0,
                            float* __restrict__ ws)
{
  int idx = blockIdx.x*blockDim.x + threadIdx.x;
  const int total = SZ_S + SZ_V + SZ_T + SZ_W2T + 24;
  for (; idx < total; idx += gridDim.x*blockDim.x) {
    int t = idx;
    if (t < SZ_S) { int f = t & 127; ws[OFF_SA+t] = species[f]; continue; }
    t -= SZ_S;
    if (t < SZ_V) { ws[OFF_VA+t] = 0.f; continue; }
    t -= SZ_V;
    if (t < SZ_T) {
      int g = t & 63;
      float a = 0.f;
      for (int f=0; f<FS; f++) a = fmaf(species[f], Wsv0[f*FV+g], a);
      ws[OFF_T0+t] = a; continue;
    }
    t -= SZ_T;
    if (t < SZ_W2T) {
      int j = t&63; int c = (t>>6)%ROUT; int l = t/(ROUT*HID);
      ws[OFF_W2T+t] = Wr2[l*HID*ROUT + j*ROUT + c]; continue;
    }
    t -= SZ_W2T;
    { int bb=t/3, c3=t-bb*3;
      float a=0.f;
      for(int n=0;n<NN;n++) a += x[(bb*NN+n)*3+c3];
      ws[OFF_COM+t] = a*(1.0f/128.0f); }
  }
}

// one block per (batch, receiver k); 320 threads = 5 waves; lane tid = channel c in [0,320)
__global__ __launch_bounds__(320, 4) void layer_kernel(
    const float* __restrict__ pos,
    const float* __restrict__ sIn,    // [b][n][f]
    const float* __restrict__ vIn,    // [b][n][f*3+c3]
    const float* __restrict__ tIn,    // [b][n][g]
    float* __restrict__ sOut,
    float* __restrict__ vOut,
    float* __restrict__ tOut,         // may be null
    const float* __restrict__ Wr1l,   // (8,64)
    const float* __restrict__ W2Tl,   // (320,64) c-major
    const float* __restrict__ WmixSl, // (192,128)
    const float* __restrict__ WmixVl, // (128,64)
    const float* __restrict__ WsvNext)// (128,64) or null
{
  const int tid = threadIdx.x;
  const int b   = blockIdx.x >> 7;
  const int k   = blockIdx.x & 127;

  __shared__ float  hidL[128*HSTR];   // 34.8 KB
  __shared__ float4 vhatL[128];
  __shared__ float  aggS[192];
  __shared__ float  aggV1[192];
  __shared__ float  aggV2[192];
  __shared__ float  sNew[FS];

  const float* pb = pos + b*NN*3;

  // ---- phase 0: threads 0..127 compute hidden[i][64] + vhat[i] into LDS ----
  if (tid < 128){
    const int i = tid;
    float pkx=pb[k*3+0], pky=pb[k*3+1], pkz=pb[k*3+2];
    float pix=pb[i*3+0], piy=pb[i*3+1], piz=pb[i*3+2];
    float vx=pkx-pix, vy=pky-piy, vz=pkz-piz;
    float r = sqrtf(vx*vx+vy*vy+vz*vz) + 1e-8f;
    float inv = 1.0f/r;
    float u = r*0.2f;
    float env = 0.0f;
    if (u < 1.0f && i != k){
      float u2=u*u, u6=u2*u2*u2;
      env = 1.0f - 28.0f*u6 + 48.0f*u6*u - 21.0f*u6*u2;
    }
    float coef = 0.6324555320336759f * inv * env;  // 0 for self / out-of-range
    float arg  = r * 0.6283185307179586f;
    vhatL[i] = make_float4(vx*inv, vy*inv, vz*inv, 0.f);
    float rb[NB];
    #pragma unroll
    for(int n=0;n<NB;n++) rb[n] = coef * __sinf(arg*(float)(n+1));
    float4* hrow = (float4*)(hidL + i*HSTR);
    #pragma unroll
    for(int jg=0;jg<16;jg++){
      float h0=0.f,h1=0.f,h2=0.f,h3=0.f;
      #pragma unroll
      for(int n=0;n<NB;n++){
        const float* wr = Wr1l + n*HID + jg*4;
        float rn = rb[n];
        h0 = fmaf(rn, wr[0], h0);
        h1 = fmaf(rn, wr[1], h1);
        h2 = fmaf(rn, wr[2], h2);
        h3 = fmaf(rn, wr[3], h3);
      }
      hrow[jg] = make_float4(silu_f(h0), silu_f(h1), silu_f(h2), silu_f(h3));
    }
  }
  __syncthreads();

  const int c = tid;
  // W2 row for this channel -> 64 VGPRs (loaded AFTER barrier so phase-0 regs are dead)
  float4 w2v[16];
  {
    const float4* wp = (const float4*)(W2Tl + c*HID);
    #pragma unroll
    for(int q=0;q<16;q++) w2v[q] = wp[q];
  }

  const float* sIb = sIn + (size_t)(b*NN)*FS;
  const float* vIb = vIn + (size_t)(b*NN)*(FV*3);
  const float* tIb = tIn + (size_t)(b*NN)*FV;

#define DOT_H(hvar, I) \
    float hvar; { \
      const float4* hp = (const float4*)(hidL + (I)*HSTR); \
      float h0=0.f,h1=0.f,h2=0.f,h3=0.f; \
      _Pragma("unroll") \
      for(int q=0;q<16;q++){ float4 hh=hp[q]; \
        h0=fmaf(hh.x,w2v[q].x,h0); h1=fmaf(hh.y,w2v[q].y,h1); \
        h2=fmaf(hh.z,w2v[q].z,h2); h3=fmaf(hh.w,w2v[q].w,h3); } \
      hvar=(h0+h1)+(h2+h3); }

  if (c < FS){
    float acc0 = 0.f;
    #pragma unroll 2
    for (int i=0;i<128;i++){
      DOT_H(h, i);
      acc0 = fmaf(h, sIb[i*FS + c], acc0);
    }
    aggS[c] = acc0 * (1.0f/128.0f);
  } else if (c < FS+FV){
    const int f = c - FS;
    float acc0 = 0.f;
    #pragma unroll 2
    for (int i=0;i<128;i++){
      DOT_H(h, i);
      float4 vh = vhatL[i];
      const float* vp = vIb + i*(FV*3) + f*3;
      float dv = vp[0]*vh.x + vp[1]*vh.y + vp[2]*vh.z;
      acc0 = fmaf(h, dv, acc0);
    }
    aggS[c] = acc0 * (1.0f/128.0f);
  } else if (c < FS+2*FV){
    const int f = c - (FS+FV);
    float acc0=0.f, acc1=0.f, acc2=0.f;
    #pragma unroll 2
    for (int i=0;i<128;i++){
      DOT_H(h, i);
      float tb = h * tIb[i*FV + f];
      float4 vh = vhatL[i];
      acc0 = fmaf(tb, vh.x, acc0);
      acc1 = fmaf(tb, vh.y, acc1);
      acc2 = fmaf(tb, vh.z, acc2);
    }
    aggV1[f*3+0] = acc0*(1.0f/128.0f);
    aggV1[f*3+1] = acc1*(1.0f/128.0f);
    aggV1[f*3+2] = acc2*(1.0f/128.0f);
  } else {
    const int f = c - (FS+2*FV);
    float acc0=0.f, acc1=0.f, acc2=0.f;
    #pragma unroll 2
    for (int i=0;i<128;i++){
      DOT_H(h, i);
      const float* vp = vIb + i*(FV*3) + f*3;
      acc0 = fmaf(h, vp[0], acc0);
      acc1 = fmaf(h, vp[1], acc1);
      acc2 = fmaf(h, vp[2], acc2);
    }
    aggV2[f*3+0] = acc0*(1.0f/128.0f);
    aggV2[f*3+1] = acc1*(1.0f/128.0f);
    aggV2[f*3+2] = acc2*(1.0f/128.0f);
  }
#undef DOT_H
  __syncthreads();

  // ---- epilogue: s update on threads 0..127; V update on threads 128..319 ----
  if (tid < FS){
    float sk = sIb[k*FS + tid];
    float a0=0.f, a1=0.f;
    #pragma unroll 4
    for (int cc=0; cc<192; cc+=2){
      a0 = fmaf(aggS[cc],   WmixSl[cc*FS+tid],     a0);
      a1 = fmaf(aggS[cc+1], WmixSl[(cc+1)*FS+tid], a1);
    }
    float sn = sk + silu_f(a0+a1);
    sNew[tid] = sn;
    sOut[(b*NN+k)*FS + tid] = sn;
  } else {
    const int idx = tid - FS;           // 0..191
    const int g = idx/3, c3 = idx - g*3;
    float a0=0.f, a1=0.f;
    #pragma unroll 4
    for (int f=0; f<FV; f++){
      a0 = fmaf(aggV1[f*3+c3], WmixVl[f*FV+g],      a0);
      a1 = fmaf(aggV2[f*3+c3], WmixVl[(f+FV)*FV+g], a1);
    }
    vOut[(b*NN+k)*(FV*3) + idx] = vIb[k*(FV*3)+idx] + a0 + a1;
  }
  __syncthreads();
  // ---- t for next layer (from updated s) ----
  if (tOut != nullptr && tid < FV){
    float a0=0.f, a1=0.f;
    #pragma unroll 4
    for (int f=0; f<FS; f+=2){
      a0 = fmaf(sNew[f],   WsvNext[f*FV+tid],     a0);
      a1 = fmaf(sNew[f+1], WsvNext[(f+1)*FV+tid], a1);
    }
    tOut[(b*NN+k)*FV + tid] = a0+a1;
  }
}

__global__ __launch_bounds__(128, 2) void out_kernel(
    const float* __restrict__ sT,     // [b][n][f]
    const float* __restrict__ vT,     // [b][n][f*3+c3]
    const float* __restrict__ WoutS,
    const float* __restrict__ WoutV,
    const float* __restrict__ comv,
    float* __restrict__ out)
{
  const int tid = threadIdx.x;
  const int b = blockIdx.x >> 7;
  const int k = blockIdx.x & 127;
  __shared__ float sL[FS];
  __shared__ float vL[FV*3];
  sL[tid] = sT[(b*NN+k)*FS + tid];
  for (int idx=tid; idx<192; idx+=128) vL[idx] = vT[(b*NN+k)*(FV*3) + idx];
  __syncthreads();
  {
    float a0=0.f, a1=0.f;
    #pragma unroll 4
    for(int f=0;f<FS;f+=2){
      a0 = fmaf(sL[f],   WoutS[f*FS+tid],     a0);
      a1 = fmaf(sL[f+1], WoutS[(f+1)*FS+tid], a1);
    }
    out[BATCH*NN*FV*3 + (b*NN+k)*FS + tid] = a0+a1;
  }
  for (int idx=tid; idx<192; idx+=128){
    int g = idx/3, c3 = idx-g*3;
    float a = comv[b*3+c3];
    #pragma unroll 4
    for(int f=0;f<FV;f++) a = fmaf(vL[f*3+c3], WoutV[f*FV+g], a);
    out[(b*NN+k)*FV*3 + idx] = a;
  }
}

extern "C" void kernel_launch(void* const* d_in, const int* in_sizes, int n_in,
                              void* d_out, int out_size, void* d_ws, size_t ws_size,
                              hipStream_t stream)
{
  const float* x       = (const float*)d_in[0];
  const float* species = (const float*)d_in[1];
  const float* Wr1     = (const float*)d_in[2];
  const float* Wr2     = (const float*)d_in[3];
  const float* Wsv     = (const float*)d_in[4];
  const float* WmixS   = (const float*)d_in[5];
  const float* WmixV   = (const float*)d_in[6];
  const float* WoutS   = (const float*)d_in[7];
  const float* WoutV   = (const float*)d_in[8];
  float* ws  = (float*)d_ws;
  float* out = (float*)d_out;

  float* sA  = ws + OFF_SA;
  float* sB  = ws + OFF_SB;
  float* vA  = ws + OFF_VA;
  float* vB  = ws + OFF_VB;
  float* t0  = ws + OFF_T0;
  float* t1  = ws + OFF_T1;
  float* w2t = ws + OFF_W2T;
  float* com = ws + OFF_COM;

  const int initTotal = SZ_S + SZ_V + SZ_T + SZ_W2T + 24;
  init_kernel<<<(initTotal+255)/256, 256, 0, stream>>>(x, species, Wr2, Wsv, ws);

  // layer 0: reads sA/vA/t0, writes sB/vB and t1 (t for layer 1 from updated s)
  layer_kernel<<<BATCH*NN, 320, 0, stream>>>(x, sA, vA, t0, sB, vB, t1,
      Wr1,          w2t,            WmixS,          WmixV,          Wsv + FS*FV);
  // layer 1: reads sB/vB/t1, writes sA/vA
  layer_kernel<<<BATCH*NN, 320, 0, stream>>>(x, sB, vB, t1, sA, vA, nullptr,
      Wr1 + NB*HID, w2t + ROUT*HID, WmixS + 192*FS, WmixV + 128*FV, nullptr);

  out_kernel<<<BATCH*NN, 128, 0, stream>>>(sA, vA, WoutS, WoutV, com, out);
}

// Round 4
// 210.469 us; speedup vs baseline: 12.6402x; 3.1794x over previous
//
#include <hip/hip_runtime.h>
#include <math.h>

typedef unsigned short u16;
typedef __attribute__((ext_vector_type(8))) short frag_ab;  // 8 bf16
typedef __attribute__((ext_vector_type(4))) float frag_cd;  // 4 fp32

#define BATCH 8
#define NN 128
#define FS 128
#define FV 64
#define NB 8
#define HID 64
#define ROUT 320
#define HSTRB 72    // hid bf16 LDS row stride (shorts): 144B rows -> 2-way (free) bank aliasing

// ---- ws layout (float offsets); s:[b][f][n], V:[b][f*3+c3][n], t:[b][g][n] ----
#define SZ_S (BATCH*FS*NN)
#define SZ_V (BATCH*FV*3*NN)
#define SZ_T (BATCH*FV*NN)
#define N_W2B (2*ROUT*HID)          // ushort count
#define OFF_SA 0
#define OFF_SB (OFF_SA+SZ_S)
#define OFF_VA (OFF_SB+SZ_S)
#define OFF_VB (OFF_VA+SZ_V)
#define OFF_T0 (OFF_VB+SZ_V)
#define OFF_T1 (OFF_T0+SZ_T)
#define OFF_COM (OFF_T1+SZ_T)       // 24 floats
#define OFF_W2B (OFF_COM+24)        // N_W2B ushorts = 20480 floats

__device__ __forceinline__ float silu_f(float x){ return x * (1.0f/(1.0f + __expf(-x))); }

__device__ __forceinline__ u16 f2bf(float x){
  union { float f; unsigned int u; } v; v.f = x;
  unsigned int r = v.u + 0x7fffu + ((v.u >> 16) & 1u);
  return (u16)(r >> 16);
}

__global__ void init_kernel(const float* __restrict__ x, const float* __restrict__ species,
                            const float* __restrict__ Wr2, const float* __restrict__ Wsv0,
                            float* __restrict__ ws)
{
  int idx = blockIdx.x*blockDim.x + threadIdx.x;
  const int total = SZ_S + SZ_V + SZ_T + N_W2B + 24;
  for (; idx < total; idx += gridDim.x*blockDim.x) {
    int t = idx;
    if (t < SZ_S) { int f = (t>>7)&127; ws[OFF_SA+t] = species[f]; continue; }
    t -= SZ_S;
    if (t < SZ_V) { ws[OFF_VA+t] = 0.f; continue; }
    t -= SZ_V;
    if (t < SZ_T) {
      int g = (t>>7)&63;
      float a = 0.f;
      for (int f=0; f<FS; f++) a = fmaf(species[f], Wsv0[f*FV+g], a);
      ws[OFF_T0+t] = a; continue;
    }
    t -= SZ_T;
    if (t < N_W2B) {
      // w2b[(l*320+c)*64 + j] = bf16(Wr2[l][j][c])
      int j = t & 63; int c = (t>>6)%ROUT; int l = t/(ROUT*HID);
      ((u16*)(ws+OFF_W2B))[t] = f2bf(Wr2[l*HID*ROUT + j*ROUT + c]); continue;
    }
    t -= N_W2B;
    { int bb=t/3, c3=t-bb*3;
      float a=0.f;
      for(int n=0;n<NN;n++) a += x[(bb*NN+n)*3+c3];
      ws[OFF_COM+t] = a*(1.0f/128.0f); }
  }
}

// one block per (batch, receiver k); 256 threads = 4 waves.
// Wave w owns channel strip [w*80, w*80+80) = 5 N-tiles of 16.
__global__ __launch_bounds__(256) void layer_kernel(
    const float* __restrict__ pos,
    const float* __restrict__ sIn,    // [b][f][n]
    const float* __restrict__ vIn,    // [b][f*3+c3][n]
    const float* __restrict__ tIn,    // [b][g][n]
    float* __restrict__ sOut,
    float* __restrict__ vOut,
    float* __restrict__ tOut,         // may be null
    const float* __restrict__ Wr1l,   // (8,64)
    const u16*   __restrict__ w2bl,   // (320,64) bf16, c-major
    const float* __restrict__ WmixSl, // (192,128)
    const float* __restrict__ WmixVl, // (128,64)
    const float* __restrict__ WsvNext)// (128,64) or null
{
  const int tid  = threadIdx.x;
  const int b    = blockIdx.x >> 7;
  const int k    = blockIdx.x & 127;
  const int w    = tid >> 6;
  const int lane = tid & 63;
  const int col  = lane & 15;
  const int quad = lane >> 4;

  __shared__ u16   hidB[128*HSTRB];       // 18.4 KB
  __shared__ float vhx[128], vhy[128], vhz[128];
  __shared__ float aggS[192], aggV1[192], aggV2[192], sNew[FS];

  const float* pb = pos + b*NN*3;

  // ---- phase 0: threads 0..127 compute hidden[i][64] (bf16 -> LDS) + vhat[i] ----
  if (tid < 128){
    const int i = tid;
    float vx = pb[k*3+0]-pb[i*3+0];
    float vy = pb[k*3+1]-pb[i*3+1];
    float vz = pb[k*3+2]-pb[i*3+2];
    float r = sqrtf(vx*vx+vy*vy+vz*vz) + 1e-8f;
    float inv = 1.0f/r;
    vhx[i]=vx*inv; vhy[i]=vy*inv; vhz[i]=vz*inv;
    float u = r*0.2f;
    float env = 0.0f;
    if (u < 1.0f && i != k){
      float u2=u*u, u6=u2*u2*u2;
      env = 1.0f - 28.0f*u6 + 48.0f*u6*u - 21.0f*u6*u2;
    }
    float coef = 0.6324555320336759f * inv * env;  // 0 for self / out-of-range
    float arg  = r * 0.6283185307179586f;
    float rb[NB];
    #pragma unroll
    for(int n=0;n<NB;n++) rb[n] = coef * __sinf(arg*(float)(n+1));
    u16* hrow = hidB + i*HSTRB;
    #pragma unroll
    for(int jg=0;jg<16;jg++){
      float h0=0.f,h1=0.f,h2=0.f,h3=0.f;
      #pragma unroll
      for(int n=0;n<NB;n++){
        const float* wr = Wr1l + n*HID + jg*4;
        float rn = rb[n];
        h0 = fmaf(rn, wr[0], h0);
        h1 = fmaf(rn, wr[1], h1);
        h2 = fmaf(rn, wr[2], h2);
        h3 = fmaf(rn, wr[3], h3);
      }
      ushort4 uu = make_ushort4(f2bf(silu_f(h0)), f2bf(silu_f(h1)),
                                f2bf(silu_f(h2)), f2bf(silu_f(h3)));
      *(ushort4*)(hrow + jg*4) = uu;
    }
  }

  // ---- B fragments: wave's 5 N-tiles x 2 K-halves (global, L1/L2-resident) ----
  frag_ab bfr[5][2];
  #pragma unroll
  for (int q=0;q<5;q++){
    const int c = (w*5+q)*16 + col;
    const u16* wp = w2bl + c*HID + quad*8;
    bfr[q][0] = *(const frag_ab*)(wp);
    bfr[q][1] = *(const frag_ab*)(wp + 32);
  }

  __syncthreads();

  const float* sIb = sIn + b*FS*NN;
  const float* vIb = vIn + b*FV*3*NN;
  const float* tIb = tIn + b*FV*NN;

  float pA[5] = {0.f,0.f,0.f,0.f,0.f};
  float pX[5] = {0.f,0.f,0.f,0.f,0.f};
  float pY[5] = {0.f,0.f,0.f,0.f,0.f};
  float pZ[5] = {0.f,0.f,0.f,0.f,0.f};

  for (int mt=0; mt<8; mt++){
    const int i0 = mt*16 + quad*4;
    const frag_ab a0 = *(const frag_ab*)&hidB[(mt*16+col)*HSTRB + quad*8];
    const frag_ab a1 = *(const frag_ab*)&hidB[(mt*16+col)*HSTRB + 32 + quad*8];
    const float4 hx4 = *(const float4*)&vhx[i0];
    const float4 hy4 = *(const float4*)&vhy[i0];
    const float4 hz4 = *(const float4*)&vhz[i0];
    #pragma unroll
    for (int q=0;q<5;q++){
      frag_cd acc = {0.f,0.f,0.f,0.f};
      acc = __builtin_amdgcn_mfma_f32_16x16x32_bf16(a0, bfr[q][0], acc, 0,0,0);
      acc = __builtin_amdgcn_mfma_f32_16x16x32_bf16(a1, bfr[q][1], acc, 0,0,0);
      const int ntg = w*5+q;
      const int c = ntg*16 + col;
      if (ntg < 8){
        // m0a: fac = s[i][c]
        float4 s4 = *(const float4*)&sIb[c*NN + i0];
        pA[q] += acc[0]*s4.x + acc[1]*s4.y + acc[2]*s4.z + acc[3]*s4.w;
      } else if (ntg < 12){
        // m0b: fac = V[i,f,:]·vhat[i]
        const int f = c - FS;
        float4 vx4 = *(const float4*)&vIb[(f*3+0)*NN + i0];
        float4 vy4 = *(const float4*)&vIb[(f*3+1)*NN + i0];
        float4 vz4 = *(const float4*)&vIb[(f*3+2)*NN + i0];
        float d0 = vx4.x*hx4.x + vy4.x*hy4.x + vz4.x*hz4.x;
        float d1 = vx4.y*hx4.y + vy4.y*hy4.y + vz4.y*hz4.y;
        float d2 = vx4.z*hx4.z + vy4.z*hy4.z + vz4.z*hz4.z;
        float d3 = vx4.w*hx4.w + vy4.w*hy4.w + vz4.w*hz4.w;
        pA[q] += acc[0]*d0 + acc[1]*d1 + acc[2]*d2 + acc[3]*d3;
      } else if (ntg < 16){
        // m1a: tb = H * t[i,f]; acc into 3 components via vhat
        const int f = c - (FS+FV);
        float4 t4 = *(const float4*)&tIb[f*NN + i0];
        float t0_ = acc[0]*t4.x, t1_ = acc[1]*t4.y, t2_ = acc[2]*t4.z, t3_ = acc[3]*t4.w;
        pX[q] += t0_*hx4.x + t1_*hx4.y + t2_*hx4.z + t3_*hx4.w;
        pY[q] += t0_*hy4.x + t1_*hy4.y + t2_*hy4.z + t3_*hy4.w;
        pZ[q] += t0_*hz4.x + t1_*hz4.y + t2_*hz4.z + t3_*hz4.w;
      } else {
        // m1b: fac = V[i,f,c3]
        const int f = c - (FS+2*FV);
        float4 vx4 = *(const float4*)&vIb[(f*3+0)*NN + i0];
        float4 vy4 = *(const float4*)&vIb[(f*3+1)*NN + i0];
        float4 vz4 = *(const float4*)&vIb[(f*3+2)*NN + i0];
        pX[q] += acc[0]*vx4.x + acc[1]*vx4.y + acc[2]*vx4.z + acc[3]*vx4.w;
        pY[q] += acc[0]*vy4.x + acc[1]*vy4.y + acc[2]*vy4.z + acc[3]*vy4.w;
        pZ[q] += acc[0]*vz4.x + acc[1]*vz4.y + acc[2]*vz4.z + acc[3]*vz4.w;
      }
    }
  }

  // ---- cross-quad reduce + stage to LDS ----
  #pragma unroll
  for (int q=0;q<5;q++){
    const int ntg = w*5+q;
    if (ntg < 12){
      float v = pA[q];
      v += __shfl_xor(v, 16, 64);
      v += __shfl_xor(v, 32, 64);
      if (lane < 16) aggS[ntg*16 + lane] = v * (1.0f/128.0f);
    } else {
      float x = pX[q]; x += __shfl_xor(x,16,64); x += __shfl_xor(x,32,64);
      float y = pY[q]; y += __shfl_xor(y,16,64); y += __shfl_xor(y,32,64);
      float z = pZ[q]; z += __shfl_xor(z,16,64); z += __shfl_xor(z,32,64);
      if (lane < 16){
        const int c = ntg*16 + lane;
        if (ntg < 16){
          const int f = c - (FS+FV);
          aggV1[f*3+0]=x*(1.0f/128.0f); aggV1[f*3+1]=y*(1.0f/128.0f); aggV1[f*3+2]=z*(1.0f/128.0f);
        } else {
          const int f = c - (FS+2*FV);
          aggV2[f*3+0]=x*(1.0f/128.0f); aggV2[f*3+1]=y*(1.0f/128.0f); aggV2[f*3+2]=z*(1.0f/128.0f);
        }
      }
    }
  }
  __syncthreads();

  // ---- epilogue: s update ----
  if (tid < FS){
    float sk = sIb[tid*NN + k];
    float a0=0.f, a1=0.f;
    #pragma unroll 4
    for (int cc=0; cc<192; cc+=2){
      a0 = fmaf(aggS[cc],   WmixSl[cc*FS+tid],     a0);
      a1 = fmaf(aggS[cc+1], WmixSl[(cc+1)*FS+tid], a1);
    }
    float sn = sk + silu_f(a0+a1);
    sNew[tid] = sn;
    sOut[(b*FS+tid)*NN + k] = sn;
  }
  // ---- epilogue: V update ----
  if (tid < 192){
    const int g = tid/3, c3 = tid - g*3;
    float a0=0.f, a1=0.f;
    #pragma unroll 4
    for (int f=0; f<FV; f++){
      a0 = fmaf(aggV1[f*3+c3], WmixVl[f*FV+g],      a0);
      a1 = fmaf(aggV2[f*3+c3], WmixVl[(f+FV)*FV+g], a1);
    }
    vOut[(b*FV*3 + tid)*NN + k] = vIb[tid*NN + k] + a0 + a1;
  }
  __syncthreads();
  // ---- t for next layer (from updated s) ----
  if (tOut != nullptr && tid < FV){
    float a0=0.f, a1=0.f;
    #pragma unroll 4
    for (int f=0; f<FS; f+=2){
      a0 = fmaf(sNew[f],   WsvNext[f*FV+tid],     a0);
      a1 = fmaf(sNew[f+1], WsvNext[(f+1)*FV+tid], a1);
    }
    tOut[(b*FV+tid)*NN + k] = a0+a1;
  }
}

__global__ __launch_bounds__(128) void out_kernel(
    const float* __restrict__ sT,     // [b][f][n]
    const float* __restrict__ vT,     // [b][f*3+c3][n]
    const float* __restrict__ WoutS,
    const float* __restrict__ WoutV,
    const float* __restrict__ comv,
    float* __restrict__ out)
{
  const int tid = threadIdx.x;
  const int b = blockIdx.x >> 7;
  const int k = blockIdx.x & 127;
  __shared__ float sL[FS];
  __shared__ float vL[FV*3];
  sL[tid] = sT[(b*FS+tid)*NN + k];
  for (int idx=tid; idx<192; idx+=128) vL[idx] = vT[(b*FV*3+idx)*NN + k];
  __syncthreads();
  {
    float a0=0.f, a1=0.f;
    #pragma unroll 4
    for(int f=0;f<FS;f+=2){
      a0 = fmaf(sL[f],   WoutS[f*FS+tid],     a0);
      a1 = fmaf(sL[f+1], WoutS[(f+1)*FS+tid], a1);
    }
    out[BATCH*NN*FV*3 + (b*NN+k)*FS + tid] = a0+a1;
  }
  for (int idx=tid; idx<192; idx+=128){
    int g = idx/3, c3 = idx-g*3;
    float a = comv[b*3+c3];
    #pragma unroll 4
    for(int f=0;f<FV;f++) a = fmaf(vL[f*3+c3], WoutV[f*FV+g], a);
    out[(b*NN+k)*FV*3 + idx] = a;
  }
}

extern "C" void kernel_launch(void* const* d_in, const int* in_sizes, int n_in,
                              void* d_out, int out_size, void* d_ws, size_t ws_size,
                              hipStream_t stream)
{
  const float* x       = (const float*)d_in[0];
  const float* species = (const float*)d_in[1];
  const float* Wr1     = (const float*)d_in[2];
  const float* Wr2     = (const float*)d_in[3];
  const float* Wsv     = (const float*)d_in[4];
  const float* WmixS   = (const float*)d_in[5];
  const float* WmixV   = (const float*)d_in[6];
  const float* WoutS   = (const float*)d_in[7];
  const float* WoutV   = (const float*)d_in[8];
  float* ws  = (float*)d_ws;
  float* out = (float*)d_out;

  float* sA  = ws + OFF_SA;
  float* sB  = ws + OFF_SB;
  float* vA  = ws + OFF_VA;
  float* vB  = ws + OFF_VB;
  float* t0  = ws + OFF_T0;
  float* t1  = ws + OFF_T1;
  float* com = ws + OFF_COM;
  u16*   w2b = (u16*)(ws + OFF_W2B);

  const int initTotal = SZ_S + SZ_V + SZ_T + N_W2B + 24;
  init_kernel<<<(initTotal+255)/256, 256, 0, stream>>>(x, species, Wr2, Wsv, ws);

  // layer 0: reads sA/vA/t0, writes sB/vB and t1 (t for layer 1 from updated s)
  layer_kernel<<<BATCH*NN, 256, 0, stream>>>(x, sA, vA, t0, sB, vB, t1,
      Wr1,          w2b,            WmixS,          WmixV,          Wsv + FS*FV);
  // layer 1: reads sB/vB/t1, writes sA/vA
  layer_kernel<<<BATCH*NN, 256, 0, stream>>>(x, sB, vB, t1, sA, vA, nullptr,
      Wr1 + NB*HID, w2b + ROUT*HID, WmixS + 192*FS, WmixV + 128*FV, nullptr);

  out_kernel<<<BATCH*NN, 128, 0, stream>>>(sA, vA, WoutS, WoutV, com, out);
}